// Round 5
// baseline (146.686 us; speedup 1.0000x reference)
//
#include <hip/hip_runtime.h>
#include <hip/hip_bf16.h>
#include <stdint.h>

// KANExpert: out[b,j] = sum_{i,g} basis(x[b,i])[g] * coeff[i,j,g] * scaling[i,j]
// == GEMM M=4096(batch) N=512(out) K=4096(=512 in_dim * 8 basis), bf16 MFMA.
//
// R8 (2nd submit; broker timeout): R3 falsified the poison theory: the
// 256 MiB ws fill (~44 us) runs UNCONDITIONALLY (even with d_ws unused), and
// module __device__ globals were +16 us slower than ws (114.2 vs 98.5) with
// identical compute. So: scratch back in d_ws (free — it's poisoned anyway),
// and attack the real budget (prep+gemm ~54 us) by FUSING the A-side (basis)
// into the gemm:
//   - kill the 32 MiB Ag intermediate (32w + 32r + 8r(x) ~ 72 MiB ~ 11 us)
//   - gemm stages x (2 KB/tile) via width-4 global_load_lds in the same
//     depth-3 ring as B (4 loads/tile total -> vmcnt counts unchanged),
//     computes basis in-register, ds_writes the A-tile (2-stage LDS).
//   - Wt prep stays: compresses the 64 MiB coeff read 16:1 for B's 64-fold
//     reuse in the gemm.
// Per-iter: vm-wait, bar, stageA(VALU+ds_write), lgkm0, bar, MFMA, bar, issue.

#define BATCH   4096
#define IN_DIM  512
#define OUT_DIM 512
#define KDIM    (IN_DIM * 8)   // 4096
#define NKT     (KDIM / 64)    // 64 K-tiles

typedef short short8 __attribute__((ext_vector_type(8)));
typedef float f32x4  __attribute__((ext_vector_type(4)));

// gfx9 s_waitcnt immediates: vmcnt low4 | expcnt<<4 | lgkmcnt<<8 (vmcnt hi @14)
#define WAIT_VM8 0xF78   // vmcnt(8), lgkm/exp unconstrained
#define WAIT_VM4 0xF74   // vmcnt(4)
#define WAIT_VM0 0xF70   // vmcnt(0)

// float -> bf16 bits, round-to-nearest-even
__device__ __forceinline__ unsigned short f2bf(float f) {
  union { float f; unsigned int u; } v; v.f = f;
  unsigned int r = v.u + 0x7FFFu + ((v.u >> 16) & 1u);
  return (unsigned short)(r >> 16);
}

// Uniform cubic B-spline window: x in [-1,1), h=0.4. m = floor((x+1)/h) in [0,4].
__device__ __forceinline__ void bspline_win(float xv, float* w, int* mm) {
  float t = (xv + 1.0f) * 2.5f;
  int m = (int)t;
  m = m < 0 ? 0 : (m > 4 ? 4 : m);
  float u  = t - (float)m;
  float u2 = u * u, u3 = u2 * u, om = 1.0f - u;
  w[0] = om * om * om * (1.0f / 6.0f);
  w[1] = (3.0f * u3 - 6.0f * u2 + 4.0f) * (1.0f / 6.0f);
  w[2] = (-3.0f * u3 + 3.0f * u2 + 3.0f * u + 1.0f) * (1.0f / 6.0f);
  w[3] = u3 * (1.0f / 6.0f);
  *mm = m;
}

__device__ __forceinline__ short8 basis_pack8(float xv) {
  float w[4]; int m;
  bspline_win(xv, w, &m);
  short8 h = {};
#pragma unroll
  for (int g = 0; g < 8; ++g) {
    int d = g - m + 3;
    float v = (d == 0) ? w[0] : (d == 1) ? w[1] : (d == 2) ? w[2] : (d == 3) ? w[3] : 0.0f;
    h[g] = (short)f2bf(v);
  }
  return h;
}

__device__ __forceinline__ void async_load16(const void* g, void* l) {
  __builtin_amdgcn_global_load_lds(
      (__attribute__((address_space(1))) void*)(uintptr_t)g,
      (__attribute__((address_space(3))) void*)(unsigned int)(uintptr_t)l,
      16, 0, 0);
}

__device__ __forceinline__ void async_load4(const void* g, void* l) {
  __builtin_amdgcn_global_load_lds(
      (__attribute__((address_space(1))) void*)(uintptr_t)g,
      (__attribute__((address_space(3))) void*)(unsigned int)(uintptr_t)l,
      4, 0, 0);
}

// ---- W^T pack: Wt[j*KDIM + i*8 + g] = coeff[i,j,g] * scaling[i,j] --------
__global__ void kan_prep_w(const float* __restrict__ coeff,
                           const float* __restrict__ scaling,
                           unsigned short* __restrict__ Wt) {
  int idx = blockIdx.x * 256 + threadIdx.x;   // i*512 + j
  int i = idx >> 9, j = idx & 511;
  float s = scaling[idx];
  const float4* cp = reinterpret_cast<const float4*>(coeff) + (size_t)idx * 2;
  float4 c0 = cp[0], c1 = cp[1];
  short8 h;
  h[0] = (short)f2bf(c0.x * s); h[1] = (short)f2bf(c0.y * s);
  h[2] = (short)f2bf(c0.z * s); h[3] = (short)f2bf(c0.w * s);
  h[4] = (short)f2bf(c1.x * s); h[5] = (short)f2bf(c1.y * s);
  h[6] = (short)f2bf(c1.z * s); h[7] = (short)f2bf(c1.w * s);
  *reinterpret_cast<short8*>(Wt + (size_t)j * KDIM + i * 8) = h;
}

// ---- fused pipelined 64x64x64 GEMM -------------------------------------
// B + x in a depth-3 global_load_lds ring (4 insts/tile: 2 B wide + 2 x
// narrow -> vmcnt protocol identical to R6). A computed in-kernel:
// stageA reads xs (linear, conflict-free), basis_pack8, ds_write_b128 into
// As[kt&1] with the XOR-swizzled layout compute() expects.
__global__ __launch_bounds__(256, 2)
void kan_gemm_f(const float* __restrict__ x,
                const unsigned short* __restrict__ Wt,
                float* __restrict__ out) {
  __shared__ unsigned short As[2][64 * 64];   // 2 x 8 KB (computed)
  __shared__ unsigned short Bs[3][64 * 64];   // 3 x 8 KB (ring)
  __shared__ float          xs[3][64 * 8];    // 3 x 2 KB (ring)

  const int tid  = threadIdx.x;
  const int lane = tid & 63;
  const int wid  = tid >> 6;
  const int wm = wid >> 1, wn = wid & 1;
  const int ln = lane & 15, quad = lane >> 4;

  const int b    = blockIdx.x;
  const int row0 = (b & 63) * 64;           // XCD = b%8: row-panel L2-pinned
  const int col0 = (b >> 6) * 64;

  f32x4 acc[2][2] = {};

  const int lr = lane >> 3;                 // staging row within 8-row inst
  const int cg = (lane & 7) ^ lr;           // XOR-swizzled 16B chunk (B side)

  const unsigned short* bRow = Wt + (size_t)(col0 + wid * 16 + lr) * KDIM + cg * 8;
  // x source: lane covers (row = wid*16 + lane>>3, col = lane&7) of the tile
  const float* xSrc = x + (size_t)(row0 + wid * 16 + (lane >> 3)) * IN_DIM + (lane & 7);

  // issue tile kt's loads into ring stage st: 2 B-insts (16B) + 2 x-insts (4B)
  auto issue = [&](int kt, int st) {
    const int k0 = kt * 64;
#pragma unroll
    for (int t = 0; t < 2; ++t) {
      const int rbase = wid * 16 + t * 8;                       // wave-uniform
      async_load16(bRow + (size_t)t * 8 * KDIM + k0, &Bs[st][rbase * 64]);
    }
#pragma unroll
    for (int t = 0; t < 2; ++t) {
      // dest: xs[st][wid*128 + t*64 + lane] (HW appends lane*4)
      async_load4(xSrc + (size_t)t * 8 * IN_DIM + kt * 8, &xs[st][wid * 128 + t * 64]);
    }
  };

  // compute basis for tile kt -> As[kt&1]. Thread covers q = tid, tid+256:
  // rn = q>>3 (row), il = q&7 (x col in tile). xs read is linear (2-way, free);
  // As write slot = il ^ (rn&7) matches compute()'s read swizzle.
  auto stageA = [&](int kt) {
    const int sx = kt % 3, sa = kt & 1;
#pragma unroll
    for (int h2 = 0; h2 < 2; ++h2) {
      const int q  = tid + h2 * 256;
      const int rn = q >> 3, il = q & 7;
      float xv = xs[sx][q];
      short8 hh = basis_pack8(xv);
      *reinterpret_cast<short8*>(&As[sa][rn * 64 + ((il ^ (rn & 7)) * 8)]) = hh;
    }
  };

  auto compute = [&](int sa, int sb) {
#pragma unroll
    for (int kk = 0; kk < 2; ++kk) {
      short8 af[2], bfr[2];
#pragma unroll
      for (int mt = 0; mt < 2; ++mt) {
        const int r    = wm * 32 + mt * 16 + ln;
        const int slot = (kk * 4 + quad) ^ (r & 7);
        af[mt] = *reinterpret_cast<const short8*>(&As[sa][r * 64 + slot * 8]);
      }
#pragma unroll
      for (int nt = 0; nt < 2; ++nt) {
        const int c    = wn * 32 + nt * 16 + ln;
        const int slot = (kk * 4 + quad) ^ (c & 7);
        bfr[nt] = *reinterpret_cast<const short8*>(&Bs[sb][c * 64 + slot * 8]);
      }
#pragma unroll
      for (int mt = 0; mt < 2; ++mt)
#pragma unroll
        for (int nt = 0; nt < 2; ++nt)
          acc[mt][nt] = __builtin_amdgcn_mfma_f32_16x16x32_bf16(af[mt], bfr[nt], acc[mt][nt], 0, 0, 0);
    }
  };

  issue(0, 0); issue(1, 1); issue(2, 2);

  for (int kt = 0; kt < NKT - 3; ++kt) {
    const int sb = kt % 3;
    __builtin_amdgcn_s_waitcnt(WAIT_VM8);     // tile kt (x+B) in LDS
    __builtin_amdgcn_s_barrier();
    stageA(kt);                               // VALU basis -> ds_write As
    asm volatile("s_waitcnt lgkmcnt(0)" ::: "memory");  // As writes drained
    __builtin_amdgcn_s_barrier();
    compute(kt & 1, sb);
    __builtin_amdgcn_s_barrier();             // Bs/xs[sb] free to recycle
    issue(kt + 3, sb);
  }
  // tail: tiles NKT-3..NKT-1, 4 loads each outstanding
  {
    int kt = NKT - 3;
    __builtin_amdgcn_s_waitcnt(WAIT_VM8);
    __builtin_amdgcn_s_barrier();
    stageA(kt);
    asm volatile("s_waitcnt lgkmcnt(0)" ::: "memory");
    __builtin_amdgcn_s_barrier();
    compute(kt & 1, kt % 3);
  }
  {
    int kt = NKT - 2;
    __builtin_amdgcn_s_waitcnt(WAIT_VM4);
    __builtin_amdgcn_s_barrier();
    stageA(kt);
    asm volatile("s_waitcnt lgkmcnt(0)" ::: "memory");
    __builtin_amdgcn_s_barrier();
    compute(kt & 1, kt % 3);
  }
  {
    int kt = NKT - 1;
    __builtin_amdgcn_s_waitcnt(WAIT_VM0);
    __builtin_amdgcn_s_barrier();
    stageA(kt);
    asm volatile("s_waitcnt lgkmcnt(0)" ::: "memory");
    __builtin_amdgcn_s_barrier();
    compute(kt & 1, kt % 3);
  }

  // C/D layout: col = lane&15, row = quad*4 + reg
#pragma unroll
  for (int mt = 0; mt < 2; ++mt)
#pragma unroll
    for (int nt = 0; nt < 2; ++nt) {
      const int col = col0 + wn * 32 + nt * 16 + ln;
#pragma unroll
      for (int r = 0; r < 4; ++r) {
        const int row = row0 + wm * 32 + mt * 16 + quad * 4 + r;
        out[(size_t)row * OUT_DIM + col] = acc[mt][nt][r];
      }
    }
}

// ---- fallback (no ws): on-the-fly staging, 64-tile, direct store ---------
__global__ __launch_bounds__(256, 2)
void kan_gemm_fb(const float* __restrict__ x, const float* __restrict__ coeff,
                 const float* __restrict__ scaling, float* __restrict__ out) {
  __shared__ unsigned short As[64 * 64];
  __shared__ unsigned short Bs[64 * 64];

  const int tid  = threadIdx.x;
  const int lane = tid & 63;
  const int wid  = tid >> 6;
  const int wm = wid >> 1, wn = wid & 1;
  const int ln = lane & 15, quad = lane >> 4;
  const int row0 = blockIdx.y * 64;
  const int col0 = blockIdx.x * 64;

  f32x4 acc[2][2] = {};

  for (int kt = 0; kt < KDIM / 64; ++kt) {
#pragma unroll
    for (int pp = 0; pp < 2; ++pp) {
      const int p  = tid + pp * 256;
      const int rn = p & 63;
      const int il = p >> 6;
      const int sw = ((il ^ (rn & 7)) * 8);
      short8 ha = basis_pack8(x[(size_t)(row0 + rn) * IN_DIM + kt * 8 + il]);
      *reinterpret_cast<short8*>(&As[rn * 64 + sw]) = ha;
      const float* cbase = coeff + (size_t)(kt * 8 + il) * 4096 + (size_t)(col0 + rn) * 8;
      float4 c0 = reinterpret_cast<const float4*>(cbase)[0];
      float4 c1 = reinterpret_cast<const float4*>(cbase)[1];
      float s = scaling[(size_t)(kt * 8 + il) * OUT_DIM + col0 + rn];
      short8 hb;
      hb[0] = (short)f2bf(c0.x * s); hb[1] = (short)f2bf(c0.y * s);
      hb[2] = (short)f2bf(c0.z * s); hb[3] = (short)f2bf(c0.w * s);
      hb[4] = (short)f2bf(c1.x * s); hb[5] = (short)f2bf(c1.y * s);
      hb[6] = (short)f2bf(c1.z * s); hb[7] = (short)f2bf(c1.w * s);
      *reinterpret_cast<short8*>(&Bs[rn * 64 + sw]) = hb;
    }
    __syncthreads();
#pragma unroll
    for (int kk = 0; kk < 2; ++kk) {
      short8 af[2], bfr[2];
#pragma unroll
      for (int mt = 0; mt < 2; ++mt) {
        const int r  = wm * 32 + mt * 16 + ln;
        const int pc = (kk * 4 + quad) ^ (r & 7);
        af[mt] = *reinterpret_cast<const short8*>(&As[r * 64 + pc * 8]);
      }
#pragma unroll
      for (int nt = 0; nt < 2; ++nt) {
        const int c  = wn * 32 + nt * 16 + ln;
        const int pc = (kk * 4 + quad) ^ (c & 7);
        bfr[nt] = *reinterpret_cast<const short8*>(&Bs[c * 64 + pc * 8]);
      }
#pragma unroll
      for (int mt = 0; mt < 2; ++mt)
#pragma unroll
        for (int nt = 0; nt < 2; ++nt)
          acc[mt][nt] = __builtin_amdgcn_mfma_f32_16x16x32_bf16(af[mt], bfr[nt], acc[mt][nt], 0, 0, 0);
    }
    __syncthreads();
  }
#pragma unroll
  for (int mt = 0; mt < 2; ++mt)
#pragma unroll
    for (int nt = 0; nt < 2; ++nt) {
      const int col = col0 + wn * 32 + nt * 16 + ln;
#pragma unroll
      for (int r = 0; r < 4; ++r) {
        const int row = row0 + wm * 32 + mt * 16 + quad * 4 + r;
        out[(size_t)row * OUT_DIM + col] = acc[mt][nt][r];
      }
    }
}

// ---- launch ------------------------------------------------------------
extern "C" void kernel_launch(void* const* d_in, const int* in_sizes, int n_in,
                              void* d_out, int out_size, void* d_ws, size_t ws_size,
                              hipStream_t stream) {
  const float* x       = (const float*)d_in[0];
  const float* coeff   = (const float*)d_in[1];
  const float* scaling = (const float*)d_in[2];
  float* out = (float*)d_out;

  const size_t needW = (size_t)OUT_DIM * KDIM * 2;   // 4 MB bf16 W^T

  if (ws_size >= needW) {
    unsigned short* Wt = (unsigned short*)d_ws;      // rewritten every call
    kan_prep_w<<<(IN_DIM * OUT_DIM) / 256, 256, 0, stream>>>(coeff, scaling, Wt);
    kan_gemm_f<<<(BATCH / 64) * (OUT_DIM / 64), 256, 0, stream>>>(x, Wt, out);
  } else {
    kan_gemm_fb<<<dim3(OUT_DIM / 64, BATCH / 64), 256, 0, stream>>>(x, coeff, scaling, out);
  }
}

// Round 6
// 100.422 us; speedup vs baseline: 1.4607x; 1.4607x over previous
//
#include <hip/hip_runtime.h>
#include <hip/hip_bf16.h>
#include <stdint.h>

// KANExpert: out[b,j] = sum_{i,g} basis(x[b,i])[g] * coeff[i,j,g] * scaling[i,j]
// == GEMM M=4096(batch) N=512(out) K=4096(=512 in_dim * 8 basis), bf16 MFMA.
//
// R9: R8's in-loop basis fusion FAILED (gemm 82us, VALUBusy 39%/MfmaUtil 8%:
// basis_pack8 ~85 VALU insts serialized between barriers). Revert to
// prep(Ag,Wt in d_ws) -> gemm. Attack the gemm's LDS-read bound (~40us,
// 1 KB LDS per MFMA at 32x32 wave tiles): move to 128x128 block tiles with
// 64x64 wave tiles (0.5 KB/MFMA) + SPLIT-K=4 so the grid stays at 512 blocks
// (2/CU, full machine). Partials (4 x 8 MB f32) in d_ws + float4 reduce.
// Staging/sync protocol is R6's proven one: global_load_lds w=16, XOR
// swizzle, raw s_barrier, counted vmcnt(8), depth-2 ring (64 KB LDS).

#define BATCH   4096
#define IN_DIM  512
#define OUT_DIM 512
#define KDIM    (IN_DIM * 8)     // 4096
#define SPLITK  4
#define KSPAN   (KDIM / SPLITK)  // 1024 per block
#define NKS     (KSPAN / 64)     // 16 K-steps per block

typedef short short8 __attribute__((ext_vector_type(8)));
typedef float f32x4  __attribute__((ext_vector_type(4)));

// gfx9 s_waitcnt immediates: vmcnt low4 @[3:0] (hi2 @[15:14]), exp @[6:4], lgkm @[11:8]
#define WAIT_VM8 0xF78   // vmcnt(8), lgkm/exp unconstrained
#define WAIT_VM0 0xF70   // vmcnt(0)

// float -> bf16 bits, round-to-nearest-even
__device__ __forceinline__ unsigned short f2bf(float f) {
  union { float f; unsigned int u; } v; v.f = f;
  unsigned int r = v.u + 0x7FFFu + ((v.u >> 16) & 1u);
  return (unsigned short)(r >> 16);
}

// Uniform cubic B-spline window: x in [-1,1), h=0.4. m = floor((x+1)/h) in [0,4].
__device__ __forceinline__ void bspline_win(float xv, float* w, int* mm) {
  float t = (xv + 1.0f) * 2.5f;
  int m = (int)t;
  m = m < 0 ? 0 : (m > 4 ? 4 : m);
  float u  = t - (float)m;
  float u2 = u * u, u3 = u2 * u, om = 1.0f - u;
  w[0] = om * om * om * (1.0f / 6.0f);
  w[1] = (3.0f * u3 - 6.0f * u2 + 4.0f) * (1.0f / 6.0f);
  w[2] = (-3.0f * u3 + 3.0f * u2 + 3.0f * u + 1.0f) * (1.0f / 6.0f);
  w[3] = u3 * (1.0f / 6.0f);
  *mm = m;
}

__device__ __forceinline__ short8 basis_pack8(float xv) {
  float w[4]; int m;
  bspline_win(xv, w, &m);
  short8 h = {};
#pragma unroll
  for (int g = 0; g < 8; ++g) {
    int d = g - m + 3;
    float v = (d == 0) ? w[0] : (d == 1) ? w[1] : (d == 2) ? w[2] : (d == 3) ? w[3] : 0.0f;
    h[g] = (short)f2bf(v);
  }
  return h;
}

__device__ __forceinline__ void async_load16(const void* g, void* l) {
  __builtin_amdgcn_global_load_lds(
      (__attribute__((address_space(1))) void*)(uintptr_t)g,
      (__attribute__((address_space(3))) void*)(unsigned int)(uintptr_t)l,
      16, 0, 0);
}

// ---- fused precompute: basis (blocks 0..8191) + W^T pack (8192..9215) ----
__global__ void kan_prep(const float* __restrict__ x,
                         const float* __restrict__ coeff,
                         const float* __restrict__ scaling,
                         unsigned short* __restrict__ Ag,
                         unsigned short* __restrict__ Wt) {
  const int b = blockIdx.x;
  if (b < (BATCH * IN_DIM) / 256) {
    int idx = b * 256 + threadIdx.x;
    short8 h = basis_pack8(x[idx]);
    *reinterpret_cast<short8*>(Ag + (size_t)idx * 8) = h;
  } else {
    int idx = (b - (BATCH * IN_DIM) / 256) * 256 + threadIdx.x;  // i*512 + j
    int i = idx >> 9, j = idx & 511;
    float s = scaling[idx];
    const float4* cp = reinterpret_cast<const float4*>(coeff) + (size_t)idx * 2;
    float4 c0 = cp[0], c1 = cp[1];
    short8 h;
    h[0] = (short)f2bf(c0.x * s); h[1] = (short)f2bf(c0.y * s);
    h[2] = (short)f2bf(c0.z * s); h[3] = (short)f2bf(c0.w * s);
    h[4] = (short)f2bf(c1.x * s); h[5] = (short)f2bf(c1.y * s);
    h[6] = (short)f2bf(c1.z * s); h[7] = (short)f2bf(c1.w * s);
    *reinterpret_cast<short8*>(Wt + (size_t)j * KDIM + i * 8) = h;
  }
}

// ---- split-K 128x128x64 GEMM, 64x64 wave tiles, depth-2 LDS ring ---------
// 256 thr = 4 waves (2x2 grid, each wave owns 64x64 = 4x4 of 16x16x32).
// Grid 512: b -> ks = b&3 (K quarter), mt = (b>>2)&31 (row tile),
// nt = b>>7 (col tile). The 4 nt-sharers of one A panel are b, b+128, ...
// (same b%8 -> same XCD -> A panel L2-resident).
// Protocol per iter kt (stage st = kt&1):
//   s_waitcnt vmcnt(8)  -- own 8 loads of tile kt retired; kt+1 in flight
//   s_barrier; compute(st); s_barrier; issue tile kt+2 -> st
__global__ __launch_bounds__(256, 2)
void kan_gemm_s(const unsigned short* __restrict__ Ag,
                const unsigned short* __restrict__ Wt,
                float* __restrict__ Pt) {
  __shared__ unsigned short As[2][128 * 64];   // 2 x 16 KB
  __shared__ unsigned short Bs[2][128 * 64];   // 2 x 16 KB

  const int tid  = threadIdx.x;
  const int lane = tid & 63;
  const int wid  = tid >> 6;
  const int wm = wid >> 1, wn = wid & 1;
  const int ln = lane & 15, quad = lane >> 4;

  const int b    = blockIdx.x;
  const int ks   = b & 3;
  const int mt   = (b >> 2) & 31;
  const int nt   = b >> 7;
  const int row0 = mt * 128;
  const int col0 = nt * 128;
  const int k0   = ks * KSPAN;

  f32x4 acc[4][4] = {};

  const int lr = lane >> 3;                 // staging row within 8-row inst
  const int cg = (lane & 7) ^ lr;           // XOR-swizzled 16B chunk to fetch

  const unsigned short* aRow = Ag + (size_t)(row0 + wid * 32 + lr) * KDIM + k0 + cg * 8;
  const unsigned short* bRow = Wt + (size_t)(col0 + wid * 32 + lr) * KDIM + k0 + cg * 8;

  // issue tile kt's 8 async loads (4 A + 4 B, 8 rows each) into stage st
  auto issue = [&](int kt, int st) {
    const int kk0 = kt * 64;
#pragma unroll
    for (int t = 0; t < 4; ++t) {
      const int rbase = wid * 32 + t * 8;                       // wave-uniform
      async_load16(aRow + (size_t)t * 8 * KDIM + kk0, &As[st][rbase * 64]);
      async_load16(bRow + (size_t)t * 8 * KDIM + kk0, &Bs[st][rbase * 64]);
    }
  };

  auto compute = [&](int st) {
#pragma unroll
    for (int kk = 0; kk < 2; ++kk) {
      short8 af[4], bfr[4];
#pragma unroll
      for (int m = 0; m < 4; ++m) {
        const int r    = wm * 64 + m * 16 + ln;
        const int slot = (kk * 4 + quad) ^ (r & 7);
        af[m] = *reinterpret_cast<const short8*>(&As[st][r * 64 + slot * 8]);
      }
#pragma unroll
      for (int n = 0; n < 4; ++n) {
        const int c    = wn * 64 + n * 16 + ln;
        const int slot = (kk * 4 + quad) ^ (c & 7);
        bfr[n] = *reinterpret_cast<const short8*>(&Bs[st][c * 64 + slot * 8]);
      }
#pragma unroll
      for (int m = 0; m < 4; ++m)
#pragma unroll
        for (int n = 0; n < 4; ++n)
          acc[m][n] = __builtin_amdgcn_mfma_f32_16x16x32_bf16(af[m], bfr[n], acc[m][n], 0, 0, 0);
    }
  };

  issue(0, 0); issue(1, 1);

  for (int kt = 0; kt < NKS - 1; ++kt) {
    __builtin_amdgcn_s_waitcnt(WAIT_VM8);     // tile kt in LDS; kt+1 in flight
    __builtin_amdgcn_s_barrier();
    compute(kt & 1);
    __builtin_amdgcn_s_barrier();             // stage kt&1 free to recycle
    if (kt + 2 < NKS) issue(kt + 2, kt & 1);
  }
  __builtin_amdgcn_s_waitcnt(WAIT_VM0);
  __builtin_amdgcn_s_barrier();
  compute((NKS - 1) & 1);

  // C/D layout: col = lane&15, row = quad*4 + reg
  float* P = Pt + (size_t)ks * BATCH * OUT_DIM;
#pragma unroll
  for (int m = 0; m < 4; ++m)
#pragma unroll
    for (int n = 0; n < 4; ++n) {
      const int col = col0 + wn * 64 + n * 16 + ln;
#pragma unroll
      for (int r = 0; r < 4; ++r) {
        const int row = row0 + wm * 64 + m * 16 + quad * 4 + r;
        P[(size_t)row * OUT_DIM + col] = acc[m][n][r];
      }
    }
}

// ---- partial reduce: out = P0 + P1 + P2 + P3 (float4 per thread) ---------
__global__ __launch_bounds__(256)
void kan_reduce(const float* __restrict__ Pt, float* __restrict__ out) {
  const size_t Q = (size_t)BATCH * OUT_DIM / 4;   // 524288 float4 per partial
  const size_t t = (size_t)blockIdx.x * 256 + threadIdx.x;
  const float4* p = reinterpret_cast<const float4*>(Pt);
  float4 a = p[t], b = p[t + Q], c = p[t + 2 * Q], d = p[t + 3 * Q];
  float4 s;
  s.x = (a.x + b.x) + (c.x + d.x);
  s.y = (a.y + b.y) + (c.y + d.y);
  s.z = (a.z + b.z) + (c.z + d.z);
  s.w = (a.w + b.w) + (c.w + d.w);
  reinterpret_cast<float4*>(out)[t] = s;
}

// ---- fallback (no ws): on-the-fly staging, 64-tile, direct store ---------
__global__ __launch_bounds__(256, 2)
void kan_gemm_fb(const float* __restrict__ x, const float* __restrict__ coeff,
                 const float* __restrict__ scaling, float* __restrict__ out) {
  __shared__ unsigned short As[64 * 64];
  __shared__ unsigned short Bs[64 * 64];

  const int tid  = threadIdx.x;
  const int lane = tid & 63;
  const int wid  = tid >> 6;
  const int wm = wid >> 1, wn = wid & 1;
  const int ln = lane & 15, quad = lane >> 4;
  const int row0 = blockIdx.y * 64;
  const int col0 = blockIdx.x * 64;

  f32x4 acc[2][2] = {};

  for (int kt = 0; kt < KDIM / 64; ++kt) {
#pragma unroll
    for (int pp = 0; pp < 2; ++pp) {
      const int p  = tid + pp * 256;
      const int rn = p & 63;
      const int il = p >> 6;
      const int sw = ((il ^ (rn & 7)) * 8);
      short8 ha = basis_pack8(x[(size_t)(row0 + rn) * IN_DIM + kt * 8 + il]);
      *reinterpret_cast<short8*>(&As[rn * 64 + sw]) = ha;
      const float* cbase = coeff + (size_t)(kt * 8 + il) * 4096 + (size_t)(col0 + rn) * 8;
      float4 c0 = reinterpret_cast<const float4*>(cbase)[0];
      float4 c1 = reinterpret_cast<const float4*>(cbase)[1];
      float s = scaling[(size_t)(kt * 8 + il) * OUT_DIM + col0 + rn];
      short8 hb;
      hb[0] = (short)f2bf(c0.x * s); hb[1] = (short)f2bf(c0.y * s);
      hb[2] = (short)f2bf(c0.z * s); hb[3] = (short)f2bf(c0.w * s);
      hb[4] = (short)f2bf(c1.x * s); hb[5] = (short)f2bf(c1.y * s);
      hb[6] = (short)f2bf(c1.z * s); hb[7] = (short)f2bf(c1.w * s);
      *reinterpret_cast<short8*>(&Bs[rn * 64 + sw]) = hb;
    }
    __syncthreads();
#pragma unroll
    for (int kk = 0; kk < 2; ++kk) {
      short8 af[2], bfr[2];
#pragma unroll
      for (int mt = 0; mt < 2; ++mt) {
        const int r  = wm * 32 + mt * 16 + ln;
        const int pc = (kk * 4 + quad) ^ (r & 7);
        af[mt] = *reinterpret_cast<const short8*>(&As[r * 64 + pc * 8]);
      }
#pragma unroll
      for (int nt = 0; nt < 2; ++nt) {
        const int c  = wn * 32 + nt * 16 + ln;
        const int pc = (kk * 4 + quad) ^ (c & 7);
        bfr[nt] = *reinterpret_cast<const short8*>(&Bs[c * 64 + pc * 8]);
      }
#pragma unroll
      for (int mt = 0; mt < 2; ++mt)
#pragma unroll
        for (int nt = 0; nt < 2; ++nt)
          acc[mt][nt] = __builtin_amdgcn_mfma_f32_16x16x32_bf16(af[mt], bfr[nt], acc[mt][nt], 0, 0, 0);
    }
    __syncthreads();
  }
#pragma unroll
  for (int mt = 0; mt < 2; ++mt)
#pragma unroll
    for (int nt = 0; nt < 2; ++nt) {
      const int col = col0 + wn * 32 + nt * 16 + ln;
#pragma unroll
      for (int r = 0; r < 4; ++r) {
        const int row = row0 + wm * 32 + mt * 16 + quad * 4 + r;
        out[(size_t)row * OUT_DIM + col] = acc[mt][nt][r];
      }
    }
}

// ---- launch ------------------------------------------------------------
extern "C" void kernel_launch(void* const* d_in, const int* in_sizes, int n_in,
                              void* d_out, int out_size, void* d_ws, size_t ws_size,
                              hipStream_t stream) {
  const float* x       = (const float*)d_in[0];
  const float* coeff   = (const float*)d_in[1];
  const float* scaling = (const float*)d_in[2];
  float* out = (float*)d_out;

  const size_t offW = (size_t)BATCH * KDIM * 2;            // Ag: 32 MB
  const size_t offP = offW + (size_t)OUT_DIM * KDIM * 2;   // Wt:  4 MB
  const size_t need = offP + (size_t)SPLITK * BATCH * OUT_DIM * 4;  // P: 32 MB

  if (ws_size >= need) {
    unsigned short* Ag = (unsigned short*)d_ws;
    unsigned short* Wt = (unsigned short*)((char*)d_ws + offW);
    float*          Pt = (float*)((char*)d_ws + offP);
    kan_prep<<<(BATCH * IN_DIM) / 256 + (IN_DIM * OUT_DIM) / 256, 256, 0, stream>>>(
        x, coeff, scaling, Ag, Wt);
    kan_gemm_s<<<(BATCH / 128) * (OUT_DIM / 128) * SPLITK, 256, 0, stream>>>(Ag, Wt, Pt);
    kan_reduce<<<(BATCH * OUT_DIM / 4) / 256, 256, 0, stream>>>(Pt, out);
  } else {
    kan_gemm_fb<<<dim3(OUT_DIM / 64, BATCH / 64), 256, 0, stream>>>(x, coeff, scaling, out);
  }
}